// Round 1
// baseline (283.939 us; speedup 1.0000x reference)
//
#include <hip/hip_runtime.h>
#include <hip/hip_bf16.h>
#include <math.h>

typedef __bf16 bf16x8 __attribute__((ext_vector_type(8)));
typedef float floatx4 __attribute__((ext_vector_type(4)));

#define DK   1536   // inner dim D
#define MROWS 4096  // B*L
#define NOUT 1536   // first GEMM output dim
#define OUTC 23     // second GEMM output dim
#define AFF_SZ (MROWS * 12)

// round-to-nearest-even fp32 -> bf16 bits (finite inputs only)
__device__ __forceinline__ unsigned short f2bf(float f) {
    unsigned int u = __float_as_uint(f);
    u += 0x7fffu + ((u >> 16) & 1u);
    return (unsigned short)(u >> 16);
}

// ---------------------------------------------------------------------------
// Kernel 1: H = gelu(x @ w1^T + b1)   [M=4096, N=1536, K=1536]
// A (x): M x K fp32 row-major.  Bm (w1): N x K fp32 row-major (already B^T).
// 128x128 block tile, 256 threads = 4 waves in 2x2, each wave 64x64.
// fp32 -> bf16 conversion fused into LDS staging.
// ---------------------------------------------------------------------------
__global__ __launch_bounds__(256, 2)
void gemm1_kernel(const float* __restrict__ A, const float* __restrict__ Bm,
                  const float* __restrict__ b1, float* __restrict__ H)
{
    // +8 bf16 pad -> row stride 144 B: 16-lane row reads alias 2-way (free)
    __shared__ __align__(16) unsigned short As[128][72];
    __shared__ __align__(16) unsigned short Bs[128][72];

    const int tid    = threadIdx.x;
    const int wave   = tid >> 6;
    const int lane   = tid & 63;
    const int wm     = (wave & 1) * 64;
    const int wn     = (wave >> 1) * 64;
    const int lane15 = lane & 15;
    const int quad   = lane >> 4;

    const int row0 = blockIdx.x * 128;
    const int col0 = blockIdx.y * 128;

    floatx4 acc[4][4] = {};

    for (int k0 = 0; k0 < DK; k0 += 64) {
        __syncthreads();
        // stage 128x64 fp32 -> bf16 for A and B; 16 threads cover one row
        #pragma unroll
        for (int i = 0; i < 8; ++i) {
            int c  = tid + 256 * i;
            int r  = c >> 4;            // 0..127
            int c4 = (c & 15) << 2;     // 0..60
            float4 va = *(const float4*)(A + (size_t)(row0 + r) * DK + k0 + c4);
            unsigned int lo = f2bf(va.x) | ((unsigned int)f2bf(va.y) << 16);
            unsigned int hi = f2bf(va.z) | ((unsigned int)f2bf(va.w) << 16);
            *(uint2*)(&As[r][c4]) = make_uint2(lo, hi);
            float4 vb = *(const float4*)(Bm + (size_t)(col0 + r) * DK + k0 + c4);
            lo = f2bf(vb.x) | ((unsigned int)f2bf(vb.y) << 16);
            hi = f2bf(vb.z) | ((unsigned int)f2bf(vb.w) << 16);
            *(uint2*)(&Bs[r][c4]) = make_uint2(lo, hi);
        }
        __syncthreads();

        #pragma unroll
        for (int ks = 0; ks < 2; ++ks) {
            bf16x8 af[4], bfr[4];
            #pragma unroll
            for (int mt = 0; mt < 4; ++mt)
                af[mt] = *(const bf16x8*)(&As[wm + mt * 16 + lane15][ks * 32 + quad * 8]);
            #pragma unroll
            for (int nt = 0; nt < 4; ++nt)
                bfr[nt] = *(const bf16x8*)(&Bs[wn + nt * 16 + lane15][ks * 32 + quad * 8]);
            #pragma unroll
            for (int mt = 0; mt < 4; ++mt)
                #pragma unroll
                for (int nt = 0; nt < 4; ++nt)
                    acc[mt][nt] = __builtin_amdgcn_mfma_f32_16x16x32_bf16(
                        af[mt], bfr[nt], acc[mt][nt], 0, 0, 0);
        }
    }

    // epilogue: + b1, exact GELU, store fp32
    #pragma unroll
    for (int mt = 0; mt < 4; ++mt)
        #pragma unroll
        for (int nt = 0; nt < 4; ++nt)
            #pragma unroll
            for (int r = 0; r < 4; ++r) {
                int row = row0 + wm + mt * 16 + quad * 4 + r;
                int col = col0 + wn + nt * 16 + lane15;
                float v = acc[mt][nt][r] + b1[col];
                v = 0.5f * v * (1.0f + erff(v * 0.70710678118654752f));
                H[(size_t)row * NOUT + col] = v;
            }
}

// ---------------------------------------------------------------------------
// Kernel 2: per-row LayerNorm + p = h_ln @ w2^T + b2 + rotation geometry.
// 4 rows per 256-thread block -> 1024 blocks; w2 (141 KB) stays L2-resident.
// ---------------------------------------------------------------------------
__global__ __launch_bounds__(256, 4)
void head_kernel(const float* __restrict__ H, const float* __restrict__ ln_g,
                 const float* __restrict__ ln_b, const float* __restrict__ w2,
                 const float* __restrict__ b2, const float* __restrict__ affine,
                 const int* __restrict__ amask, float* __restrict__ out)
{
    __shared__ float red[8];
    __shared__ float stats[2];
    __shared__ float p_lds[OUTC];

    const int tid = threadIdx.x, lane = tid & 63, wave = tid >> 6;

    for (int rr = 0; rr < 4; ++rr) {
        const int row = blockIdx.x * 4 + rr;
        const float* h = H + (size_t)row * DK;

        // -------- LN stats --------
        float s = 0.f, ss = 0.f;
        for (int d = tid; d < DK; d += 256) {
            float v = h[d];
            s += v; ss += v * v;
        }
        #pragma unroll
        for (int off = 32; off > 0; off >>= 1) {
            s  += __shfl_down(s, off, 64);
            ss += __shfl_down(ss, off, 64);
        }
        if (lane == 0) { red[wave] = s; red[4 + wave] = ss; }
        if (tid < OUTC) p_lds[tid] = 0.f;
        __syncthreads();
        if (tid == 0) {
            float S  = red[0] + red[1] + red[2] + red[3];
            float SS = red[4] + red[5] + red[6] + red[7];
            float mu  = S * (1.f / DK);
            float var = SS * (1.f / DK) - mu * mu;
            stats[0] = mu;
            stats[1] = 1.f / sqrtf(var + 1e-5f);
        }
        __syncthreads();
        const float mu = stats[0], rstd = stats[1];

        // -------- p = LN(h) @ w2^T --------
        float acc[OUTC];
        #pragma unroll
        for (int o = 0; o < OUTC; ++o) acc[o] = 0.f;
        for (int d = tid; d < DK; d += 256) {
            float hn = (h[d] - mu) * rstd * ln_g[d] + ln_b[d];
            #pragma unroll
            for (int o = 0; o < OUTC; ++o)
                acc[o] += hn * w2[o * DK + d];
        }
        #pragma unroll
        for (int o = 0; o < OUTC; ++o) {
            float v = acc[o];
            #pragma unroll
            for (int off = 32; off > 0; off >>= 1) v += __shfl_down(v, off, 64);
            if (lane == 0) atomicAdd(&p_lds[o], v);
        }
        __syncthreads();

        // -------- geometry (thread 0, ~100 FLOP) --------
        if (tid == 0) {
            float p[OUTC];
            #pragma unroll
            for (int o = 0; o < OUTC; ++o) p[o] = p_lds[o] + b2[o];

            float trans[3] = { p[0] * 10.f, p[1] * 10.f, p[2] * 10.f };
            float xv[3] = { p[3], p[4], p[5] };
            float yv[3] = { p[6], p[7], p[8] };
            float xn = sqrtf(xv[0]*xv[0] + xv[1]*xv[1] + xv[2]*xv[2]) + 1e-5f;
            xv[0] /= xn; xv[1] /= xn; xv[2] /= xn;
            float yn = sqrtf(yv[0]*yv[0] + yv[1]*yv[1] + yv[2]*yv[2]) + 1e-5f;
            yv[0] /= yn; yv[1] /= yn; yv[2] /= yn;

            // Ru = graham_schmidt(-xv, yv)
            float a0 = -xv[0], a1 = -xv[1], a2 = -xv[2];
            float inv = 1.f / sqrtf(a0*a0 + a1*a1 + a2*a2 + 1e-12f);
            float e0x = a0 * inv, e0y = a1 * inv, e0z = a2 * inv;
            float c = e0x*yv[0] + e0y*yv[1] + e0z*yv[2];
            float e1x = yv[0] - e0x * c, e1y = yv[1] - e0y * c, e1z = yv[2] - e0z * c;
            inv = 1.f / sqrtf(e1x*e1x + e1y*e1y + e1z*e1z + 1e-12f);
            e1x *= inv; e1y *= inv; e1z *= inv;
            float e2x = e0y*e1z - e0z*e1y;
            float e2y = e0z*e1x - e0x*e1z;
            float e2z = e0x*e1y - e0y*e1x;

            float Ru[3][3] = { { e0x, e1x, e2x },
                               { e0y, e1y, e2y },
                               { e0z, e1z, e2z } };
            float tu[3] = { trans[0], trans[1], trans[2] };
            if (amask[row] == 0) {
                Ru[0][0]=1.f; Ru[0][1]=0.f; Ru[0][2]=0.f;
                Ru[1][0]=0.f; Ru[1][1]=1.f; Ru[1][2]=0.f;
                Ru[2][0]=0.f; Ru[2][1]=0.f; Ru[2][2]=1.f;
                tu[0]=tu[1]=tu[2]=0.f;
            }

            const float* af = affine + (size_t)row * 12;
            float R0[3][3] = { { af[0], af[1], af[2] },
                               { af[3], af[4], af[5] },
                               { af[6], af[7], af[8] } };
            float t0[3] = { af[9], af[10], af[11] };

            float R[3][3], t[3];
            #pragma unroll
            for (int i = 0; i < 3; ++i) {
                #pragma unroll
                for (int j = 0; j < 3; ++j)
                    R[i][j] = R0[i][0]*Ru[0][j] + R0[i][1]*Ru[1][j] + R0[i][2]*Ru[2][j];
                t[i] = R0[i][0]*tu[0] + R0[i][1]*tu[1] + R0[i][2]*tu[2] + t0[i];
            }

            float* oa = out + (size_t)row * 12;
            #pragma unroll
            for (int i = 0; i < 3; ++i) {
                #pragma unroll
                for (int j = 0; j < 3; ++j) oa[i*3 + j] = R[i][j];
                oa[9 + i] = t[i];
            }

            const float BB[3][3] = { { -0.525f, 1.363f, 0.f },
                                     {  0.f,    0.f,   0.f },
                                     {  1.526f, 0.f,   0.f } };
            float* op = out + AFF_SZ + (size_t)row * 9;
            #pragma unroll
            for (int a = 0; a < 3; ++a)
                #pragma unroll
                for (int i = 0; i < 3; ++i)
                    op[a*3 + i] = R[i][0]*BB[a][0] + R[i][1]*BB[a][1] + R[i][2]*BB[a][2] + t[i];
        }
        __syncthreads();
    }
}

extern "C" void kernel_launch(void* const* d_in, const int* in_sizes, int n_in,
                              void* d_out, int out_size, void* d_ws, size_t ws_size,
                              hipStream_t stream) {
    const float* x      = (const float*)d_in[0];
    const float* affine = (const float*)d_in[1];
    const int*   amask  = (const int*)  d_in[2];
    const float* w1     = (const float*)d_in[3];
    const float* b1     = (const float*)d_in[4];
    const float* ln_g   = (const float*)d_in[5];
    const float* ln_b   = (const float*)d_in[6];
    const float* w2     = (const float*)d_in[7];
    const float* b2     = (const float*)d_in[8];
    float* out = (float*)d_out;
    float* H   = (float*)d_ws;   // 4096 x 1536 fp32 = 25.2 MB scratch

    dim3 g1(MROWS / 128, NOUT / 128);   // 32 x 12 = 384 blocks
    gemm1_kernel<<<g1, 256, 0, stream>>>(x, w1, b1, H);
    head_kernel<<<MROWS / 4, 256, 0, stream>>>(H, ln_g, ln_b, w2, b2, affine, amask, out);
}

// Round 2
// 196.704 us; speedup vs baseline: 1.4435x; 1.4435x over previous
//
#include <hip/hip_runtime.h>
#include <hip/hip_bf16.h>
#include <math.h>

typedef __bf16 bf16x8 __attribute__((ext_vector_type(8)));
typedef float floatx4 __attribute__((ext_vector_type(4)));

#define DK    1536   // inner dim D
#define MROWS 4096   // B*L
#define NOUT  1536   // first GEMM output dim
#define OUTC  23     // second GEMM output dim
#define AFF_SZ (MROWS * 12)

// round-to-nearest-even fp32 -> bf16 bits (finite inputs only)
__device__ __forceinline__ unsigned short f2bf(float f) {
    unsigned int u = __float_as_uint(f);
    u += 0x7fffu + ((u >> 16) & 1u);
    return (unsigned short)(u >> 16);
}

// ---------------------------------------------------------------------------
// Kernel 1: H = gelu(x @ w1^T + b1)   [M=4096, N=1536, K=1536]
// 128x128 block tile, 256 thr = 4 waves (2x2), wave tile 64x64, BK=64.
// Register-prefetch pipeline: all 16 float4 loads of tile k+1 are issued
// into named registers before the MFMAs of tile k, hiding L2/L3 latency.
// ---------------------------------------------------------------------------
__global__ __launch_bounds__(256, 2)
void gemm1_kernel(const float* __restrict__ A, const float* __restrict__ Bm,
                  const float* __restrict__ b1, float* __restrict__ H)
{
    // +8 bf16 pad -> row stride 144 B (2-way bank alias: free per m136)
    __shared__ __align__(16) unsigned short As[128][72];
    __shared__ __align__(16) unsigned short Bs[128][72];

    const int tid    = threadIdx.x;
    const int wave   = tid >> 6;
    const int lane   = tid & 63;
    const int wm     = (wave & 1) * 64;
    const int wn     = (wave >> 1) * 64;
    const int lane15 = lane & 15;
    const int quad   = lane >> 4;

    const int row0 = blockIdx.x * 128;
    const int col0 = blockIdx.y * 128;

    const int rbase = tid >> 4;          // 0..15
    const int c4    = (tid & 15) << 2;   // 0,4,...,60

    const float* Ab = A  + (size_t)(row0 + rbase) * DK + c4;
    const float* Bb = Bm + (size_t)(col0 + rbase) * DK + c4;

    floatx4 acc[4][4] = {};
    float4 pa[8], pb[8];

    // prologue: issue loads for k0 = 0
    #pragma unroll
    for (int i = 0; i < 8; ++i) {
        pa[i] = *(const float4*)(Ab + (size_t)(16 * i) * DK);
        pb[i] = *(const float4*)(Bb + (size_t)(16 * i) * DK);
    }

    for (int k0 = 0; k0 < DK; k0 += 64) {
        // convert + store tile k (waits on the prefetch loads)
        #pragma unroll
        for (int i = 0; i < 8; ++i) {
            unsigned int lo = f2bf(pa[i].x) | ((unsigned int)f2bf(pa[i].y) << 16);
            unsigned int hi = f2bf(pa[i].z) | ((unsigned int)f2bf(pa[i].w) << 16);
            *(uint2*)(&As[rbase + 16 * i][c4]) = make_uint2(lo, hi);
            lo = f2bf(pb[i].x) | ((unsigned int)f2bf(pb[i].y) << 16);
            hi = f2bf(pb[i].z) | ((unsigned int)f2bf(pb[i].w) << 16);
            *(uint2*)(&Bs[rbase + 16 * i][c4]) = make_uint2(lo, hi);
        }
        // issue loads for tile k+1 (pure global, no LDS dependency)
        if (k0 + 64 < DK) {
            #pragma unroll
            for (int i = 0; i < 8; ++i) {
                pa[i] = *(const float4*)(Ab + (size_t)(16 * i) * DK + k0 + 64);
                pb[i] = *(const float4*)(Bb + (size_t)(16 * i) * DK + k0 + 64);
            }
        }
        __syncthreads();

        #pragma unroll
        for (int ks = 0; ks < 2; ++ks) {
            bf16x8 af[4], bfr[4];
            #pragma unroll
            for (int mt = 0; mt < 4; ++mt)
                af[mt] = *(const bf16x8*)(&As[wm + mt * 16 + lane15][ks * 32 + quad * 8]);
            #pragma unroll
            for (int nt = 0; nt < 4; ++nt)
                bfr[nt] = *(const bf16x8*)(&Bs[wn + nt * 16 + lane15][ks * 32 + quad * 8]);
            #pragma unroll
            for (int mt = 0; mt < 4; ++mt)
                #pragma unroll
                for (int nt = 0; nt < 4; ++nt)
                    acc[mt][nt] = __builtin_amdgcn_mfma_f32_16x16x32_bf16(
                        af[mt], bfr[nt], acc[mt][nt], 0, 0, 0);
        }
        __syncthreads();   // all waves done reading LDS before next overwrite
    }

    // epilogue: + b1, exact GELU, store fp32
    #pragma unroll
    for (int mt = 0; mt < 4; ++mt)
        #pragma unroll
        for (int nt = 0; nt < 4; ++nt)
            #pragma unroll
            for (int r = 0; r < 4; ++r) {
                int row = row0 + wm + mt * 16 + quad * 4 + r;
                int col = col0 + wn + nt * 16 + lane15;
                float v = acc[mt][nt][r] + b1[col];
                v = 0.5f * v * (1.0f + erff(v * 0.70710678118654752f));
                H[(size_t)row * NOUT + col] = v;
            }
}

// ---------------------------------------------------------------------------
// Kernel 2: 8 rows per 256-thread block (512 blocks).
// Phase 1: stats + stash h in LDS (one HBM read of H total).
// Phase 1b: normalize in place.
// Phase 2: wave w computes outputs o in [6w, 6w+6) over full D — w2 read
//          once per 8 rows (72 MB L2 total vs 578 MB before).
// Phase 3: threads 0..7 do the 3x3 geometry for one row each.
// ---------------------------------------------------------------------------
__global__ __launch_bounds__(256)
void head_kernel(const float* __restrict__ H, const float* __restrict__ ln_g,
                 const float* __restrict__ ln_b, const float* __restrict__ w2,
                 const float* __restrict__ b2, const float* __restrict__ affine,
                 const int* __restrict__ amask, float* __restrict__ out)
{
    __shared__ __align__(16) float hs[8][DK];   // 49152 B
    __shared__ float st[8][2];
    __shared__ float pr[8][24];

    const int tid  = threadIdx.x;
    const int lane = tid & 63;
    const int wave = tid >> 6;
    const int row8 = blockIdx.x * 8;

    // -------- phase 1: load h, stats, stash in LDS (2 rows per wave) -----
    #pragma unroll
    for (int rr = 0; rr < 2; ++rr) {
        const int r = wave * 2 + rr;
        const float4* src = (const float4*)(H + (size_t)(row8 + r) * DK);
        float s = 0.f, ss = 0.f;
        #pragma unroll
        for (int j = 0; j < 6; ++j) {
            float4 v = src[lane + 64 * j];
            *(float4*)&hs[r][(lane + 64 * j) * 4] = v;
            s  += v.x + v.y + v.z + v.w;
            ss += v.x * v.x + v.y * v.y + v.z * v.z + v.w * v.w;
        }
        #pragma unroll
        for (int off = 32; off > 0; off >>= 1) {
            s  += __shfl_down(s, off, 64);
            ss += __shfl_down(ss, off, 64);
        }
        if (lane == 0) {
            float mu  = s * (1.f / DK);
            float var = ss * (1.f / DK) - mu * mu;
            st[r][0] = mu;
            st[r][1] = 1.f / sqrtf(var + 1e-5f);
        }
    }
    __syncthreads();

    // -------- phase 1b: normalize in place --------
    #pragma unroll
    for (int j = 0; j < 12; ++j) {
        int idx = tid + 256 * j;            // float4 index, 0..3071
        int r   = idx / 384;
        int d4  = idx - r * 384;
        float mu = st[r][0], rstd = st[r][1];
        float4 g4 = *(const float4*)(ln_g + d4 * 4);
        float4 b4 = *(const float4*)(ln_b + d4 * 4);
        float4 v  = *(float4*)&hs[r][d4 * 4];
        v.x = (v.x - mu) * rstd * g4.x + b4.x;
        v.y = (v.y - mu) * rstd * g4.y + b4.y;
        v.z = (v.z - mu) * rstd * g4.z + b4.z;
        v.w = (v.w - mu) * rstd * g4.w + b4.w;
        *(float4*)&hs[r][d4 * 4] = v;
    }
    __syncthreads();

    // -------- phase 2: p[r][o] for this wave's o-slice --------
    {
        const int o0 = wave * 6;
        float acc[6][8];
        #pragma unroll
        for (int oo = 0; oo < 6; ++oo)
            #pragma unroll
            for (int r = 0; r < 8; ++r) acc[oo][r] = 0.f;

        for (int j = 0; j < 24; ++j) {
            const int d = lane + 64 * j;
            float hv[8];
            #pragma unroll
            for (int r = 0; r < 8; ++r) hv[r] = hs[r][d];
            #pragma unroll
            for (int oo = 0; oo < 6; ++oo) {
                if (o0 + oo < OUTC) {
                    float wv = w2[(size_t)(o0 + oo) * DK + d];
                    #pragma unroll
                    for (int r = 0; r < 8; ++r) acc[oo][r] += wv * hv[r];
                }
            }
        }
        #pragma unroll
        for (int oo = 0; oo < 6; ++oo)
            #pragma unroll
            for (int r = 0; r < 8; ++r) {
                float v = acc[oo][r];
                #pragma unroll
                for (int off = 32; off > 0; off >>= 1) v += __shfl_down(v, off, 64);
                if (lane == 0 && o0 + oo < OUTC) pr[r][o0 + oo] = v + b2[o0 + oo];
            }
    }
    __syncthreads();

    // -------- phase 3: geometry, one row per thread (tid 0..7) --------
    if (tid < 8) {
        const int row = row8 + tid;
        float p[OUTC];
        #pragma unroll
        for (int o = 0; o < OUTC; ++o) p[o] = pr[tid][o];

        float trans[3] = { p[0] * 10.f, p[1] * 10.f, p[2] * 10.f };
        float xv[3] = { p[3], p[4], p[5] };
        float yv[3] = { p[6], p[7], p[8] };
        float xn = sqrtf(xv[0]*xv[0] + xv[1]*xv[1] + xv[2]*xv[2]) + 1e-5f;
        xv[0] /= xn; xv[1] /= xn; xv[2] /= xn;
        float yn = sqrtf(yv[0]*yv[0] + yv[1]*yv[1] + yv[2]*yv[2]) + 1e-5f;
        yv[0] /= yn; yv[1] /= yn; yv[2] /= yn;

        // Ru = graham_schmidt(-xv, yv)
        float a0 = -xv[0], a1 = -xv[1], a2 = -xv[2];
        float inv = 1.f / sqrtf(a0*a0 + a1*a1 + a2*a2 + 1e-12f);
        float e0x = a0 * inv, e0y = a1 * inv, e0z = a2 * inv;
        float c = e0x*yv[0] + e0y*yv[1] + e0z*yv[2];
        float e1x = yv[0] - e0x * c, e1y = yv[1] - e0y * c, e1z = yv[2] - e0z * c;
        inv = 1.f / sqrtf(e1x*e1x + e1y*e1y + e1z*e1z + 1e-12f);
        e1x *= inv; e1y *= inv; e1z *= inv;
        float e2x = e0y*e1z - e0z*e1y;
        float e2y = e0z*e1x - e0x*e1z;
        float e2z = e0x*e1y - e0y*e1x;

        float Ru[3][3] = { { e0x, e1x, e2x },
                           { e0y, e1y, e2y },
                           { e0z, e1z, e2z } };
        float tu[3] = { trans[0], trans[1], trans[2] };
        if (amask[row] == 0) {
            Ru[0][0]=1.f; Ru[0][1]=0.f; Ru[0][2]=0.f;
            Ru[1][0]=0.f; Ru[1][1]=1.f; Ru[1][2]=0.f;
            Ru[2][0]=0.f; Ru[2][1]=0.f; Ru[2][2]=1.f;
            tu[0]=tu[1]=tu[2]=0.f;
        }

        const float* af = affine + (size_t)row * 12;
        float R0[3][3] = { { af[0], af[1], af[2] },
                           { af[3], af[4], af[5] },
                           { af[6], af[7], af[8] } };
        float t0[3] = { af[9], af[10], af[11] };

        float R[3][3], t[3];
        #pragma unroll
        for (int i = 0; i < 3; ++i) {
            #pragma unroll
            for (int j = 0; j < 3; ++j)
                R[i][j] = R0[i][0]*Ru[0][j] + R0[i][1]*Ru[1][j] + R0[i][2]*Ru[2][j];
            t[i] = R0[i][0]*tu[0] + R0[i][1]*tu[1] + R0[i][2]*tu[2] + t0[i];
        }

        float* oa = out + (size_t)row * 12;
        #pragma unroll
        for (int i = 0; i < 3; ++i) {
            #pragma unroll
            for (int j = 0; j < 3; ++j) oa[i*3 + j] = R[i][j];
            oa[9 + i] = t[i];
        }

        const float BB[3][3] = { { -0.525f, 1.363f, 0.f },
                                 {  0.f,    0.f,   0.f },
                                 {  1.526f, 0.f,   0.f } };
        float* op = out + AFF_SZ + (size_t)row * 9;
        #pragma unroll
        for (int a = 0; a < 3; ++a)
            #pragma unroll
            for (int i = 0; i < 3; ++i)
                op[a*3 + i] = R[i][0]*BB[a][0] + R[i][1]*BB[a][1] + R[i][2]*BB[a][2] + t[i];
    }
}

extern "C" void kernel_launch(void* const* d_in, const int* in_sizes, int n_in,
                              void* d_out, int out_size, void* d_ws, size_t ws_size,
                              hipStream_t stream) {
    const float* x      = (const float*)d_in[0];
    const float* affine = (const float*)d_in[1];
    const int*   amask  = (const int*)  d_in[2];
    const float* w1     = (const float*)d_in[3];
    const float* b1     = (const float*)d_in[4];
    const float* ln_g   = (const float*)d_in[5];
    const float* ln_b   = (const float*)d_in[6];
    const float* w2     = (const float*)d_in[7];
    const float* b2     = (const float*)d_in[8];
    float* out = (float*)d_out;
    float* H   = (float*)d_ws;   // 4096 x 1536 fp32 = 25.2 MB scratch

    dim3 g1(MROWS / 128, NOUT / 128);   // 32 x 12 = 384 blocks
    gemm1_kernel<<<g1, 256, 0, stream>>>(x, w1, b1, H);
    head_kernel<<<MROWS / 8, 256, 0, stream>>>(H, ln_g, ln_b, w2, b2, affine, amask, out);
}

// Round 3
// 149.018 us; speedup vs baseline: 1.9054x; 1.3200x over previous
//
#include <hip/hip_runtime.h>
#include <hip/hip_bf16.h>
#include <math.h>

typedef __bf16 bf16x8 __attribute__((ext_vector_type(8)));
typedef float floatx4 __attribute__((ext_vector_type(4)));

#define DK    1536   // inner dim D
#define MROWS 4096   // B*L
#define NOUT  1536   // first GEMM output dim
#define OUTC  23     // second GEMM output dim
#define AFF_SZ (MROWS * 12)
#define HSTRIDE 1544 // bf16 row stride in head LDS (+8 pad)

// round-to-nearest (ties up) fp32 -> bf16 bits; 2 VALU/value amortized
__device__ __forceinline__ unsigned int pkbf(float lo, float hi) {
    unsigned int a = __float_as_uint(lo) + 0x8000u;
    unsigned int b = __float_as_uint(hi) + 0x8000u;
    return (b & 0xffff0000u) | (a >> 16);
}
__device__ __forceinline__ unsigned short f2bf1(float v) {
    return (unsigned short)((__float_as_uint(v) + 0x8000u) >> 16);
}
__device__ __forceinline__ float bflo(unsigned int u) {
    return __uint_as_float(u << 16);
}
__device__ __forceinline__ float bfhi(unsigned int u) {
    return __uint_as_float(u & 0xffff0000u);
}

// ---------------------------------------------------------------------------
// Kernel 1: Hb = bf16( gelu(x @ w1^T + b1) )   [M=4096, N=1536, K=1536]
// 128x128 tile, 256 thr = 4 waves (2x2), wave 64x64, BK=64.
// Register-prefetch of next k-tile; cheap RN bf16 packing in staging.
// ---------------------------------------------------------------------------
__global__ __launch_bounds__(256, 2)
void gemm1_kernel(const float* __restrict__ A, const float* __restrict__ Bm,
                  const float* __restrict__ b1, unsigned short* __restrict__ Hb)
{
    __shared__ __align__(16) unsigned short As[128][72];
    __shared__ __align__(16) unsigned short Bs[128][72];

    const int tid    = threadIdx.x;
    const int wave   = tid >> 6;
    const int lane   = tid & 63;
    const int wm     = (wave & 1) * 64;
    const int wn     = (wave >> 1) * 64;
    const int lane15 = lane & 15;
    const int quad   = lane >> 4;

    const int row0 = blockIdx.x * 128;
    const int col0 = blockIdx.y * 128;

    const int rbase = tid >> 4;          // 0..15
    const int c4    = (tid & 15) << 2;   // 0,4,...,60

    const float* Ab = A  + (size_t)(row0 + rbase) * DK + c4;
    const float* Bb = Bm + (size_t)(col0 + rbase) * DK + c4;

    floatx4 acc[4][4] = {};
    float4 pa[8], pb[8];

    #pragma unroll
    for (int i = 0; i < 8; ++i) {
        pa[i] = *(const float4*)(Ab + (size_t)(16 * i) * DK);
        pb[i] = *(const float4*)(Bb + (size_t)(16 * i) * DK);
    }

    for (int k0 = 0; k0 < DK; k0 += 64) {
        #pragma unroll
        for (int i = 0; i < 8; ++i) {
            unsigned int lo = pkbf(pa[i].x, pa[i].y);
            unsigned int hi = pkbf(pa[i].z, pa[i].w);
            *(uint2*)(&As[rbase + 16 * i][c4]) = make_uint2(lo, hi);
            lo = pkbf(pb[i].x, pb[i].y);
            hi = pkbf(pb[i].z, pb[i].w);
            *(uint2*)(&Bs[rbase + 16 * i][c4]) = make_uint2(lo, hi);
        }
        if (k0 + 64 < DK) {
            #pragma unroll
            for (int i = 0; i < 8; ++i) {
                pa[i] = *(const float4*)(Ab + (size_t)(16 * i) * DK + k0 + 64);
                pb[i] = *(const float4*)(Bb + (size_t)(16 * i) * DK + k0 + 64);
            }
        }
        __syncthreads();

        #pragma unroll
        for (int ks = 0; ks < 2; ++ks) {
            bf16x8 af[4], bfr[4];
            #pragma unroll
            for (int mt = 0; mt < 4; ++mt)
                af[mt] = *(const bf16x8*)(&As[wm + mt * 16 + lane15][ks * 32 + quad * 8]);
            #pragma unroll
            for (int nt = 0; nt < 4; ++nt)
                bfr[nt] = *(const bf16x8*)(&Bs[wn + nt * 16 + lane15][ks * 32 + quad * 8]);
            #pragma unroll
            for (int mt = 0; mt < 4; ++mt)
                #pragma unroll
                for (int nt = 0; nt < 4; ++nt)
                    acc[mt][nt] = __builtin_amdgcn_mfma_f32_16x16x32_bf16(
                        af[mt], bfr[nt], acc[mt][nt], 0, 0, 0);
        }
        __syncthreads();
    }

    // epilogue: + b1, exact GELU, store bf16
    #pragma unroll
    for (int mt = 0; mt < 4; ++mt)
        #pragma unroll
        for (int nt = 0; nt < 4; ++nt)
            #pragma unroll
            for (int r = 0; r < 4; ++r) {
                int row = row0 + wm + mt * 16 + quad * 4 + r;
                int col = col0 + wn + nt * 16 + lane15;
                float v = acc[mt][nt][r] + b1[col];
                v = 0.5f * v * (1.0f + erff(v * 0.70710678118654752f));
                Hb[(size_t)row * NOUT + col] = f2bf1(v);
            }
}

// ---------------------------------------------------------------------------
// Kernel 2: 8 rows/block (512 blocks, 256 thr).
// P1: load bf16 h -> LDS + LN stats (1 shuffle-reduce pair per row).
// P1b: normalize in place (bf16).
// P2: GEMM2 via mfma_16x16x32_bf16. Waves = (ntile 0/1) x (khalf 0/1);
//     K-reduction in hardware; one LDS add to merge k-halves.
// P3: geometry on threads 0..7.
// ---------------------------------------------------------------------------
__global__ __launch_bounds__(256)
void head_kernel(const unsigned short* __restrict__ Hb, const float* __restrict__ ln_g,
                 const float* __restrict__ ln_b, const float* __restrict__ w2,
                 const float* __restrict__ b2, const float* __restrict__ affine,
                 const int* __restrict__ amask, float* __restrict__ out)
{
    __shared__ __align__(16) unsigned short hb[8][HSTRIDE];
    __shared__ float st[8][2];
    __shared__ float pred[2][16][17];
    __shared__ float pr[8][32];

    const int tid    = threadIdx.x;
    const int lane   = tid & 63;
    const int wave   = tid >> 6;
    const int lane15 = lane & 15;
    const int quad   = lane >> 4;
    const int row8   = blockIdx.x * 8;

    // -------- P1: load 2 rows per wave, stats, stash raw bf16 --------
    #pragma unroll
    for (int rr = 0; rr < 2; ++rr) {
        const int r = wave * 2 + rr;
        const unsigned short* src = Hb + (size_t)(row8 + r) * DK;
        float s = 0.f, ss = 0.f;
        #pragma unroll
        for (int j = 0; j < 3; ++j) {
            const int e8 = lane + 64 * j;            // ushort8 index 0..191
            uint4 u = *(const uint4*)(src + e8 * 8);
            *(uint4*)(&hb[r][e8 * 8]) = u;
            float f0 = bflo(u.x), f1 = bfhi(u.x), f2 = bflo(u.y), f3 = bfhi(u.y);
            float f4 = bflo(u.z), f5 = bfhi(u.z), f6 = bflo(u.w), f7 = bfhi(u.w);
            s  += ((f0 + f1) + (f2 + f3)) + ((f4 + f5) + (f6 + f7));
            ss += ((f0*f0 + f1*f1) + (f2*f2 + f3*f3)) + ((f4*f4 + f5*f5) + (f6*f6 + f7*f7));
        }
        #pragma unroll
        for (int off = 32; off > 0; off >>= 1) {
            s  += __shfl_down(s, off, 64);
            ss += __shfl_down(ss, off, 64);
        }
        if (lane == 0) {
            float mu  = s * (1.f / DK);
            float var = ss * (1.f / DK) - mu * mu;
            st[r][0] = mu;
            st[r][1] = 1.f / sqrtf(var + 1e-5f);
        }
    }
    __syncthreads();

    // -------- P1b: normalize in place --------
    {
        const int r   = tid >> 5;
        const int c32 = tid & 31;
        const float mu = st[r][0], rstd = st[r][1];
        const float murstd = mu * rstd;
        #pragma unroll
        for (int jj = 0; jj < 6; ++jj) {
            const int e8 = c32 + 32 * jj;            // ushort8 unit 0..191
            const int d  = e8 * 8;
            uint4 u = *(uint4*)(&hb[r][d]);
            float4 g0 = *(const float4*)(ln_g + d);
            float4 g1 = *(const float4*)(ln_g + d + 4);
            float4 b0 = *(const float4*)(ln_b + d);
            float4 b1v = *(const float4*)(ln_b + d + 4);
            float h0 = fmaf(bflo(u.x), rstd, -murstd), h1 = fmaf(bfhi(u.x), rstd, -murstd);
            float h2 = fmaf(bflo(u.y), rstd, -murstd), h3 = fmaf(bfhi(u.y), rstd, -murstd);
            float h4 = fmaf(bflo(u.z), rstd, -murstd), h5 = fmaf(bfhi(u.z), rstd, -murstd);
            float h6 = fmaf(bflo(u.w), rstd, -murstd), h7 = fmaf(bfhi(u.w), rstd, -murstd);
            h0 = fmaf(h0, g0.x, b0.x);  h1 = fmaf(h1, g0.y, b0.y);
            h2 = fmaf(h2, g0.z, b0.z);  h3 = fmaf(h3, g0.w, b0.w);
            h4 = fmaf(h4, g1.x, b1v.x); h5 = fmaf(h5, g1.y, b1v.y);
            h6 = fmaf(h6, g1.z, b1v.z); h7 = fmaf(h7, g1.w, b1v.w);
            u.x = pkbf(h0, h1); u.y = pkbf(h2, h3);
            u.z = pkbf(h4, h5); u.w = pkbf(h6, h7);
            *(uint4*)(&hb[r][d]) = u;
        }
    }
    __syncthreads();

    // -------- P2: p = h_ln @ w2^T via MFMA --------
    {
        const int ntile = wave & 1;
        const int khalf = wave >> 1;
        const int o     = ntile * 16 + lane15;
        const int osafe = (o < OUTC) ? o : 0;
        const float* wrow = w2 + (size_t)osafe * DK;
        const int mrow  = lane15 & 7;

        floatx4 acc = {0.f, 0.f, 0.f, 0.f};
        #pragma unroll 4
        for (int kk = 0; kk < 24; ++kk) {
            const int kb = khalf * 768 + kk * 32 + quad * 8;
            bf16x8 afr = *(const bf16x8*)(&hb[mrow][kb]);
            float4 wa = *(const float4*)(wrow + kb);
            float4 wb = *(const float4*)(wrow + kb + 4);
            union { unsigned int u[4]; bf16x8 v; } bu;
            bu.u[0] = pkbf(wa.x, wa.y);
            bu.u[1] = pkbf(wa.z, wa.w);
            bu.u[2] = pkbf(wb.x, wb.y);
            bu.u[3] = pkbf(wb.z, wb.w);
            acc = __builtin_amdgcn_mfma_f32_16x16x32_bf16(afr, bu.v, acc, 0, 0, 0);
        }

        if (khalf == 1) {
            #pragma unroll
            for (int r2 = 0; r2 < 4; ++r2)
                pred[ntile][quad * 4 + r2][lane15] = acc[r2];
        }
        __syncthreads();
        if (khalf == 0) {
            #pragma unroll
            for (int r2 = 0; r2 < 4; ++r2) {
                const int row = quad * 4 + r2;
                if (row < 8 && o < OUTC)
                    pr[row][o] = acc[r2] + pred[ntile][row][lane15] + b2[o];
            }
        }
    }
    __syncthreads();

    // -------- P3: geometry, one row per thread --------
    if (tid < 8) {
        const int row = row8 + tid;
        float p[OUTC];
        #pragma unroll
        for (int oo = 0; oo < OUTC; ++oo) p[oo] = pr[tid][oo];

        float trans[3] = { p[0] * 10.f, p[1] * 10.f, p[2] * 10.f };
        float xv[3] = { p[3], p[4], p[5] };
        float yv[3] = { p[6], p[7], p[8] };
        float xn = sqrtf(xv[0]*xv[0] + xv[1]*xv[1] + xv[2]*xv[2]) + 1e-5f;
        xv[0] /= xn; xv[1] /= xn; xv[2] /= xn;
        float yn = sqrtf(yv[0]*yv[0] + yv[1]*yv[1] + yv[2]*yv[2]) + 1e-5f;
        yv[0] /= yn; yv[1] /= yn; yv[2] /= yn;

        float a0 = -xv[0], a1 = -xv[1], a2 = -xv[2];
        float inv = 1.f / sqrtf(a0*a0 + a1*a1 + a2*a2 + 1e-12f);
        float e0x = a0 * inv, e0y = a1 * inv, e0z = a2 * inv;
        float c = e0x*yv[0] + e0y*yv[1] + e0z*yv[2];
        float e1x = yv[0] - e0x * c, e1y = yv[1] - e0y * c, e1z = yv[2] - e0z * c;
        inv = 1.f / sqrtf(e1x*e1x + e1y*e1y + e1z*e1z + 1e-12f);
        e1x *= inv; e1y *= inv; e1z *= inv;
        float e2x = e0y*e1z - e0z*e1y;
        float e2y = e0z*e1x - e0x*e1z;
        float e2z = e0x*e1y - e0y*e1x;

        float Ru[3][3] = { { e0x, e1x, e2x },
                           { e0y, e1y, e2y },
                           { e0z, e1z, e2z } };
        float tu[3] = { trans[0], trans[1], trans[2] };
        if (amask[row] == 0) {
            Ru[0][0]=1.f; Ru[0][1]=0.f; Ru[0][2]=0.f;
            Ru[1][0]=0.f; Ru[1][1]=1.f; Ru[1][2]=0.f;
            Ru[2][0]=0.f; Ru[2][1]=0.f; Ru[2][2]=1.f;
            tu[0]=tu[1]=tu[2]=0.f;
        }

        const float* af = affine + (size_t)row * 12;
        float R0[3][3] = { { af[0], af[1], af[2] },
                           { af[3], af[4], af[5] },
                           { af[6], af[7], af[8] } };
        float t0[3] = { af[9], af[10], af[11] };

        float R[3][3], t[3];
        #pragma unroll
        for (int i = 0; i < 3; ++i) {
            #pragma unroll
            for (int j = 0; j < 3; ++j)
                R[i][j] = R0[i][0]*Ru[0][j] + R0[i][1]*Ru[1][j] + R0[i][2]*Ru[2][j];
            t[i] = R0[i][0]*tu[0] + R0[i][1]*tu[1] + R0[i][2]*tu[2] + t0[i];
        }

        float* oa = out + (size_t)row * 12;
        #pragma unroll
        for (int i = 0; i < 3; ++i) {
            #pragma unroll
            for (int j = 0; j < 3; ++j) oa[i*3 + j] = R[i][j];
            oa[9 + i] = t[i];
        }

        const float BB[3][3] = { { -0.525f, 1.363f, 0.f },
                                 {  0.f,    0.f,   0.f },
                                 {  1.526f, 0.f,   0.f } };
        float* op = out + AFF_SZ + (size_t)row * 9;
        #pragma unroll
        for (int a = 0; a < 3; ++a)
            #pragma unroll
            for (int i = 0; i < 3; ++i)
                op[a*3 + i] = R[i][0]*BB[a][0] + R[i][1]*BB[a][1] + R[i][2]*BB[a][2] + t[i];
    }
}

extern "C" void kernel_launch(void* const* d_in, const int* in_sizes, int n_in,
                              void* d_out, int out_size, void* d_ws, size_t ws_size,
                              hipStream_t stream) {
    const float* x      = (const float*)d_in[0];
    const float* affine = (const float*)d_in[1];
    const int*   amask  = (const int*)  d_in[2];
    const float* w1     = (const float*)d_in[3];
    const float* b1     = (const float*)d_in[4];
    const float* ln_g   = (const float*)d_in[5];
    const float* ln_b   = (const float*)d_in[6];
    const float* w2     = (const float*)d_in[7];
    const float* b2     = (const float*)d_in[8];
    float* out = (float*)d_out;
    unsigned short* Hb = (unsigned short*)d_ws;   // 4096 x 1536 bf16 = 12.6 MB

    dim3 g1(MROWS / 128, NOUT / 128);   // 384 blocks
    gemm1_kernel<<<g1, 256, 0, stream>>>(x, w1, b1, Hb);
    head_kernel<<<MROWS / 8, 256, 0, stream>>>(Hb, ln_g, ln_b, w2, b2, affine, amask, out);
}